// Round 6
// baseline (472.900 us; speedup 1.0000x reference)
//
#include <hip/hip_runtime.h>

#define IMGW 28
#define OUTW 26
#define FLAT (OUTW * OUTW)
#define NCLS 10
#define WSTR 12            // padded LDS stride for wT[f][c], 48B = b128-friendly
#define FPAD (FLAT + 2)    // 2 zeroed pad rows: masked cols may read f=676,677

// lane = image (64 imgs/block). 8 waves split the 26 output COLUMNS into
// 4-wide strips (starts 0,4,8,12,16,20,24; wave6 masks to 2 cols, wave7 idle)
// over ALL 26 rows -> all waves touch the same image cache lines => no halo
// overfetch. Conv runs from a rolling 6-row register file (static indices via
// full unroll), prefetch distance 4 bodies. FC weights come from LDS at
// wave-uniform addresses (broadcast ds_read, no bank conflicts, no serialized
// s_load chain). __launch_bounds__(512,2): 2 blocks/CU (CUDA min-blocks
// semantics on this toolchain) -> VGPR cap 128, no spill.
// Wave 6 loads ONE float4 per row (cols 24..27): two would read past the
// buffer end on the last image (round-5 crash).
__global__ __launch_bounds__(512, 2) void fused_conv_fc_kernel(
    const float* __restrict__ x,       // [B, 784]
    const float* __restrict__ conv_w,  // [3,3]
    const float* __restrict__ fc_w,    // [10, 676]
    const float* __restrict__ fc_b,    // [10]
    float* __restrict__ out)           // [B, 10]
{
    __shared__ float wT[FPAD * WSTR];       // 32544 B, wT[f*WSTR+c]
    __shared__ float part[6][64][NCLS];     // 15360 B, waves 1..6 partials

    const int tid  = threadIdx.x;
    const int lane = tid & 63;
    const int wid  = __builtin_amdgcn_readfirstlane(tid >> 6);
    const int img  = blockIdx.x * 64 + lane;

    const float* ip = x + (size_t)img * (IMGW * IMGW);

    // stage fc_w transposed: wT[f][c] = fc_w[c*FLAT+f]; zero the 2 pad rows
    for (int i = tid; i < NCLS * FLAT; i += 512) {
        int c = i / FLAT;
        int f = i - c * FLAT;
        wT[f * WSTR + c] = fc_w[i];
    }
    if (tid < 2 * WSTR) wT[FLAT * WSTR + tid] = 0.f;

    // uniform conv weights -> SGPRs
    const float cw0 = conv_w[0], cw1 = conv_w[1], cw2 = conv_w[2];
    const float cw3 = conv_w[3], cw4 = conv_w[4], cw5 = conv_w[5];
    const float cw6 = conv_w[6], cw7 = conv_w[7], cw8 = conv_w[8];

    __syncthreads();

    float acc[NCLS];
#pragma unroll
    for (int c = 0; c < NCLS; ++c) acc[c] = 0.f;

    if (wid < 7) {
        const int  c0   = (wid == 6) ? 24 : 4 * wid;  // strip start (16B-aligned)
        const int  wv   = (wid == 6) ? 2  : 4;        // valid out cols this wave
        const bool full = (wid != 6);                 // wave-uniform

        __attribute__((aligned(16))) float b[6][8]; // rolling rows (6,7 dead for w6)

#define LOADR(S, R) do {                                               \
        const float4* _p = (const float4*)(ip + (R) * IMGW + c0);      \
        *(float4*)&b[S][0] = _p[0];                                    \
        if (full) *(float4*)&b[S][4] = _p[1];                          \
    } while (0)

        if (!full) {   // keep dead slots finite (they feed masked h lanes)
#pragma unroll
            for (int s = 0; s < 6; ++s) { b[s][4] = 0.f; b[s][5] = 0.f;
                                          b[s][6] = 0.f; b[s][7] = 0.f; }
        }

#pragma unroll
        for (int s = 0; s < 6; ++s) LOADR(s, s);

#pragma unroll
        for (int r = 0; r < OUTW; ++r) {
            const int s0 = r % 6, s1 = (r + 1) % 6, s2 = (r + 2) % 6;
            const float* wrow = &wT[(r * OUTW + c0) * WSTR];
#pragma unroll
            for (int j = 0; j < 4; ++j) {
                float h = b[s0][j]     * cw0 + b[s0][j + 1] * cw1 + b[s0][j + 2] * cw2
                        + b[s1][j]     * cw3 + b[s1][j + 1] * cw4 + b[s1][j + 2] * cw5
                        + b[s2][j]     * cw6 + b[s2][j + 1] * cw7 + b[s2][j + 2] * cw8;
                h = fmaxf(h, 0.f);
                if (j >= wv) h = 0.f;   // wave-uniform mask (pad rows are zeroed)
                const float* wp = wrow + j * WSTR;
#pragma unroll
                for (int c = 0; c < NCLS; ++c)
                    acc[c] = fmaf(h, wp[c], acc[c]);
            }
            if (r + 6 < IMGW) LOADR(s0, r + 6);   // prefetch, consumed 4 bodies later
        }
#undef LOADR
    }

    if (wid >= 1 && wid < 7) {
#pragma unroll
        for (int c = 0; c < NCLS; ++c) part[wid - 1][lane][c] = acc[c];
    }
    __syncthreads();
    if (wid == 0) {
        float v[NCLS];
#pragma unroll
        for (int c = 0; c < NCLS; ++c) {
            float t = acc[c];
#pragma unroll
            for (int w = 0; w < 6; ++w) t += part[w][lane][c];
            v[c] = t + fc_b[c];
        }
        float* o = out + (size_t)img * NCLS;
#pragma unroll
        for (int q = 0; q < 5; ++q)
            *(float2*)(o + 2 * q) = make_float2(v[2 * q], v[2 * q + 1]);
    }
}

extern "C" void kernel_launch(void* const* d_in, const int* in_sizes, int n_in,
                              void* d_out, int out_size, void* d_ws, size_t ws_size,
                              hipStream_t stream) {
    const float* x      = (const float*)d_in[0];
    const float* conv_w = (const float*)d_in[1];
    const float* fc_w   = (const float*)d_in[2];
    const float* fc_b   = (const float*)d_in[3];
    float* out = (float*)d_out;

    const int nimg   = in_sizes[0] / (IMGW * IMGW);  // 32768
    const int blocks = nimg / 64;                    // 512

    hipLaunchKernelGGL(fused_conv_fc_kernel, dim3(blocks), dim3(512), 0, stream,
                       x, conv_w, fc_w, fc_b, out);
}

// Round 7
// 40.503 us; speedup vs baseline: 11.6756x; 11.6756x over previous
//
#include <hip/hip_runtime.h>

#define IMGW 28
#define OUTW 26
#define FLAT (OUTW * OUTW)
#define NCLS 10
#define WSTR 12            // padded LDS stride for wT[f][c], 48B
#define FPAD (FLAT + 2)    // 2 zeroed pad rows (masked cols read f=676,677)

// lane = image (64 imgs/block). Waves 0..6 take 4-wide output-column strips
// (starts 0,4,...,24; wave6 has 2 valid cols, wave7 idles) over all 26 rows:
// all waves read the SAME image rows -> no halo overfetch. Conv uses a 4-slot
// rolling register row-buffer; 26 rows = 6 iterations x 4 bodies (unroll 1 on
// the outer loop bounds register pressure -- round 6's full unroll spilled:
// VGPR cap 128, 727MB scratch writes) + 2 epilogue bodies. FC weights come
// from LDS at wave-uniform addresses (broadcast ds_read). Main-loop prefetch
// reaches row 27 max -> always in bounds (no OOB: round-5 crash class).
// __launch_bounds__(512,2): 2 blocks/CU (CUDA min-blocks semantics on this
// toolchain) -> VGPR cap 128.
__global__ __launch_bounds__(512, 2) void fused_conv_fc_kernel(
    const float* __restrict__ x,       // [B, 784]
    const float* __restrict__ conv_w,  // [3,3]
    const float* __restrict__ fc_w,    // [10, 676]
    const float* __restrict__ fc_b,    // [10]
    float* __restrict__ out)           // [B, 10]
{
    __shared__ float wT[FPAD * WSTR];       // 32544 B, wT[f*WSTR+c]
    __shared__ float part[6][64][NCLS];     // 15360 B, waves 1..6 partials

    const int tid  = threadIdx.x;
    const int lane = tid & 63;
    const int wid  = __builtin_amdgcn_readfirstlane(tid >> 6);
    const int img  = blockIdx.x * 64 + lane;

    const float* ip = x + (size_t)img * (IMGW * IMGW);

    // stage fc_w transposed: wT[f][c] = fc_w[c*FLAT+f]; zero the 2 pad rows
    for (int i = tid; i < NCLS * FLAT; i += 512) {
        int c = i / FLAT;
        int f = i - c * FLAT;
        wT[f * WSTR + c] = fc_w[i];
    }
    if (tid < 2 * WSTR) wT[FLAT * WSTR + tid] = 0.f;

    // uniform conv weights -> SGPRs
    const float cw0 = conv_w[0], cw1 = conv_w[1], cw2 = conv_w[2];
    const float cw3 = conv_w[3], cw4 = conv_w[4], cw5 = conv_w[5];
    const float cw6 = conv_w[6], cw7 = conv_w[7], cw8 = conv_w[8];

    __syncthreads();

    float acc[NCLS];
#pragma unroll
    for (int c = 0; c < NCLS; ++c) acc[c] = 0.f;

    if (wid < 7) {
        const int  c0   = (wid == 6) ? 24 : 4 * wid;  // 16B-aligned strip start
        const int  wv   = (wid == 6) ? 2  : 4;        // valid out cols
        const bool full = (wid != 6);                 // wave-uniform

        __attribute__((aligned(16))) float b0[8], b1[8], b2[8], b3[8];

#define LOADR(BUF, RR) do {                                            \
        const float4* _p = (const float4*)(ip + (RR) * IMGW + c0);     \
        *(float4*)&BUF[0] = _p[0];                                     \
        if (full) *(float4*)&BUF[4] = _p[1];                           \
    } while (0)

        if (!full) {   // dead slots stay finite (feed masked h only)
#pragma unroll
            for (int q = 4; q < 8; ++q) { b0[q] = 0.f; b1[q] = 0.f;
                                          b2[q] = 0.f; b3[q] = 0.f; }
        }

        LOADR(b0, 0); LOADR(b1, 1); LOADR(b2, 2); LOADR(b3, 3);

        // one output row R: conv h from rows A,B,C; prefetch row RL into L
        // (used 2 bodies later); FC from wave-uniform LDS broadcasts.
#define BODY(A, B, C, L, RL, R) do {                                   \
        float h[4];                                                    \
        _Pragma("unroll")                                              \
        for (int j = 0; j < 4; ++j) {                                  \
            float t = A[j]     * cw0 + A[j + 1] * cw1 + A[j + 2] * cw2 \
                    + B[j]     * cw3 + B[j + 1] * cw4 + B[j + 2] * cw5 \
                    + C[j]     * cw6 + C[j + 1] * cw7 + C[j + 2] * cw8;\
            t = fmaxf(t, 0.f);                                         \
            h[j] = (j >= wv) ? 0.f : t;                                \
        }                                                              \
        LOADR(L, RL);                                                  \
        const float* _w = &wT[((R) * OUTW + c0) * WSTR];               \
        _Pragma("unroll")                                              \
        for (int j = 0; j < 4; ++j)                                    \
            _Pragma("unroll")                                          \
            for (int c = 0; c < NCLS; ++c)                             \
                acc[c] = fmaf(h[j], _w[j * WSTR + c], acc[c]);         \
    } while (0)

#define BODY_LAST(A, B, C, R) do {                                    \
        float h[4];                                                    \
        _Pragma("unroll")                                              \
        for (int j = 0; j < 4; ++j) {                                  \
            float t = A[j]     * cw0 + A[j + 1] * cw1 + A[j + 2] * cw2 \
                    + B[j]     * cw3 + B[j + 1] * cw4 + B[j + 2] * cw5 \
                    + C[j]     * cw6 + C[j + 1] * cw7 + C[j + 2] * cw8;\
            t = fmaxf(t, 0.f);                                         \
            h[j] = (j >= wv) ? 0.f : t;                                \
        }                                                              \
        const float* _w = &wT[((R) * OUTW + c0) * WSTR];               \
        _Pragma("unroll")                                              \
        for (int j = 0; j < 4; ++j)                                    \
            _Pragma("unroll")                                          \
            for (int c = 0; c < NCLS; ++c)                             \
                acc[c] = fmaf(h[j], _w[j * WSTR + c], acc[c]);         \
    } while (0)

        int r = 0;
#pragma unroll 1
        for (int t6 = 0; t6 < 6; ++t6) {     // rows 0..23; loads reach row 27
            BODY(b0, b1, b2, b0, r + 4, r + 0);
            BODY(b1, b2, b3, b1, r + 5, r + 1);
            BODY(b2, b3, b0, b2, r + 6, r + 2);
            BODY(b3, b0, b1, b3, r + 7, r + 3);
            r += 4;
        }
        BODY_LAST(b0, b1, b2, 24);           // b0..b3 hold rows 24..27
        BODY_LAST(b1, b2, b3, 25);
#undef LOADR
#undef BODY
#undef BODY_LAST
    }

    if (wid >= 1 && wid < 7) {
#pragma unroll
        for (int c = 0; c < NCLS; ++c) part[wid - 1][lane][c] = acc[c];
    }
    __syncthreads();
    if (wid == 0) {
        float v[NCLS];
#pragma unroll
        for (int c = 0; c < NCLS; ++c) {
            float t = acc[c];
#pragma unroll
            for (int w = 0; w < 6; ++w) t += part[w][lane][c];
            v[c] = t + fc_b[c];
        }
        float* o = out + (size_t)img * NCLS;
#pragma unroll
        for (int q = 0; q < 5; ++q)
            *(float2*)(o + 2 * q) = make_float2(v[2 * q], v[2 * q + 1]);
    }
}

extern "C" void kernel_launch(void* const* d_in, const int* in_sizes, int n_in,
                              void* d_out, int out_size, void* d_ws, size_t ws_size,
                              hipStream_t stream) {
    const float* x      = (const float*)d_in[0];
    const float* conv_w = (const float*)d_in[1];
    const float* fc_w   = (const float*)d_in[2];
    const float* fc_b   = (const float*)d_in[3];
    float* out = (float*)d_out;

    const int nimg   = in_sizes[0] / (IMGW * IMGW);  // 32768
    const int blocks = nimg / 64;                    // 512

    hipLaunchKernelGGL(fused_conv_fc_kernel, dim3(blocks), dim3(512), 0, stream,
                       x, conv_w, fc_w, fc_b, out);
}